// Round 1
// baseline (1006.953 us; speedup 1.0000x reference)
//
#include <hip/hip_runtime.h>

#define LK(v) ((v) >= 0.f ? (v) : 0.01f * (v))

__device__ __forceinline__ float leaky(float v) { return v >= 0.f ? v : 0.01f * v; }

// ---------------------------------------------------------------------------
// Degree count over col (edges only; self-loop handled as +1 later)
__global__ void k_deg(const int* __restrict__ col, int E, int* __restrict__ deg) {
    int e = blockIdx.x * blockDim.x + threadIdx.x;
    if (e < E) atomicAdd(&deg[col[e]], 1);
}

// Hierarchical exclusive scan, part 1: per-block (256 elems)
__global__ __launch_bounds__(256) void k_scan_part(const int* __restrict__ deg,
                                                   int* __restrict__ part,
                                                   int* __restrict__ bsum, int N) {
    __shared__ int tmp[256];
    int tid = threadIdx.x;
    int i = blockIdx.x * 256 + tid;
    int v = (i < N) ? deg[i] : 0;
    tmp[tid] = v;
    __syncthreads();
    for (int ofs = 1; ofs < 256; ofs <<= 1) {
        int t = (tid >= ofs) ? tmp[tid - ofs] : 0;
        __syncthreads();
        tmp[tid] += t;
        __syncthreads();
    }
    int incl = tmp[tid];
    if (i < N) part[i] = incl - v;
    if (tid == 255) bsum[blockIdx.x] = incl;
}

// part 2: scan the block sums (NB <= 256), write total to offs[N]
__global__ __launch_bounds__(256) void k_scan_sums(const int* __restrict__ bsum,
                                                   int* __restrict__ boff, int NB,
                                                   int* __restrict__ offs_last) {
    __shared__ int tmp[256];
    int tid = threadIdx.x;
    int v = (tid < NB) ? bsum[tid] : 0;
    tmp[tid] = v;
    __syncthreads();
    for (int ofs = 1; ofs < 256; ofs <<= 1) {
        int t = (tid >= ofs) ? tmp[tid - ofs] : 0;
        __syncthreads();
        tmp[tid] += t;
        __syncthreads();
    }
    int incl = tmp[tid];
    if (tid < NB) boff[tid] = incl - v;
    if (tid == 255) offs_last[0] = incl;  // total edge count = offs[N]
}

// part 3: final offsets + pos copy + dinv = rsqrt(deg+1)
__global__ __launch_bounds__(256) void k_scan_final(const int* __restrict__ part,
                                                    const int* __restrict__ boff,
                                                    const int* __restrict__ deg,
                                                    int* __restrict__ offs,
                                                    int* __restrict__ pos,
                                                    float* __restrict__ dinv, int N) {
    int i = blockIdx.x * 256 + threadIdx.x;
    if (i < N) {
        int o = part[i] + boff[blockIdx.x];
        offs[i] = o;
        pos[i] = o;
        dinv[i] = rsqrtf((float)(deg[i] + 1));
    }
}

// CSR fill (nondeterministic intra-bucket order; only perturbs fp32 sum order)
__global__ void k_fill(const int* __restrict__ row, const int* __restrict__ col, int E,
                       int* __restrict__ pos, int* __restrict__ csr) {
    int e = blockIdx.x * blockDim.x + threadIdx.x;
    if (e < E) {
        int p = atomicAdd(&pos[col[e]], 1);
        csr[p] = row[e];
    }
}

// ---------------------------------------------------------------------------
// Fused feature front-end: x1 = concat(5 leaky-linears), x = leaky(x1 @ Wl + bl)
// 64 nodes per block, 256 threads.
__global__ __launch_bounds__(256) void k_feat(
    const float* __restrict__ screen, const float* __restrict__ des,
    const float* __restrict__ tweet, const float* __restrict__ profile,
    const float* __restrict__ personal,
    const float* __restrict__ Ws, const float* __restrict__ bs,
    const float* __restrict__ Wd, const float* __restrict__ bd,
    const float* __restrict__ Wt, const float* __restrict__ bt,
    const float* __restrict__ Wp, const float* __restrict__ bp,
    const float* __restrict__ Wpe, const float* __restrict__ bpe,
    const float* __restrict__ Wl, const float* __restrict__ bl,
    float* __restrict__ x1g, float* __restrict__ xg, int N) {
    __shared__ float xs[64][33];   // 64 nodes x 32-k chunk
    __shared__ float ws[32][17];   // W chunk 32 x 16
    __shared__ float x1s[64][65];  // assembled x1 tile
    __shared__ float wl[64][65];   // W_lin

    const int tid = threadIdx.x;
    const int n0 = blockIdx.x * 64;
    const int j16 = tid & 15;
    const int nb = (tid >> 4) * 4;

    const float* F[3] = {screen, des, tweet};
    const float* WF[3] = {Ws, Wd, Wt};
    const float* BF[3] = {bs, bd, bt};

#pragma unroll
    for (int f = 0; f < 3; ++f) {
        const float* X = F[f];
        const float* W = WF[f];
        float acc0 = 0.f, acc1 = 0.f, acc2 = 0.f, acc3 = 0.f;
        for (int k0 = 0; k0 < 768; k0 += 32) {
#pragma unroll
            for (int v = 0; v < 2; ++v) {
                int idx = tid + v * 256;     // float4 index 0..511
                int n = idx >> 3;            // 8 float4 per 32-float row
                int kk = (idx & 7) << 2;
                float4 val = make_float4(0.f, 0.f, 0.f, 0.f);
                if (n0 + n < N)
                    val = *reinterpret_cast<const float4*>(X + (size_t)(n0 + n) * 768 + k0 + kk);
                xs[n][kk] = val.x; xs[n][kk + 1] = val.y;
                xs[n][kk + 2] = val.z; xs[n][kk + 3] = val.w;
            }
            if (tid < 128) {
                int k = tid >> 2;
                int jj = (tid & 3) << 2;
                float4 w = *reinterpret_cast<const float4*>(W + (size_t)(k0 + k) * 16 + jj);
                ws[k][jj] = w.x; ws[k][jj + 1] = w.y;
                ws[k][jj + 2] = w.z; ws[k][jj + 3] = w.w;
            }
            __syncthreads();
#pragma unroll
            for (int k = 0; k < 32; ++k) {
                float w = ws[k][j16];
                acc0 += xs[nb + 0][k] * w;
                acc1 += xs[nb + 1][k] * w;
                acc2 += xs[nb + 2][k] * w;
                acc3 += xs[nb + 3][k] * w;
            }
            __syncthreads();
        }
        float bb = BF[f][j16];
        x1s[nb + 0][f * 16 + j16] = leaky(acc0 + bb);
        x1s[nb + 1][f * 16 + j16] = leaky(acc1 + bb);
        x1s[nb + 2][f * 16 + j16] = leaky(acc2 + bb);
        x1s[nb + 3][f * 16 + j16] = leaky(acc3 + bb);
    }

    // profile (5->8) and personal (7->8): one thread per node
    if (tid < 64) {
        int n = n0 + tid;
        float pv[5] = {0, 0, 0, 0, 0};
        float pev[7] = {0, 0, 0, 0, 0, 0, 0};
        if (n < N) {
#pragma unroll
            for (int i = 0; i < 5; ++i) pv[i] = profile[(size_t)n * 5 + i];
#pragma unroll
            for (int i = 0; i < 7; ++i) pev[i] = personal[(size_t)n * 7 + i];
        }
#pragma unroll
        for (int j = 0; j < 8; ++j) {
            float a = bp[j];
#pragma unroll
            for (int i = 0; i < 5; ++i) a += pv[i] * Wp[i * 8 + j];
            x1s[tid][48 + j] = leaky(a);
            float a2 = bpe[j];
#pragma unroll
            for (int i = 0; i < 7; ++i) a2 += pev[i] * Wpe[i * 8 + j];
            x1s[tid][56 + j] = leaky(a2);
        }
    }

    // stage W_lin while x1s settles
#pragma unroll
    for (int v = 0; v < 4; ++v) {
        int idx = tid + v * 256;
        int k = idx >> 4;
        int jj = (idx & 15) << 2;
        float4 w = *reinterpret_cast<const float4*>(Wl + (size_t)k * 64 + jj);
        wl[k][jj] = w.x; wl[k][jj + 1] = w.y; wl[k][jj + 2] = w.z; wl[k][jj + 3] = w.w;
    }
    __syncthreads();

    // write x1 to global
#pragma unroll
    for (int v = 0; v < 4; ++v) {
        int idx = tid + v * 256;
        int n = idx >> 4;
        int jj = (idx & 15) << 2;
        if (n0 + n < N) {
            float4 val = make_float4(x1s[n][jj], x1s[n][jj + 1], x1s[n][jj + 2], x1s[n][jj + 3]);
            *reinterpret_cast<float4*>(x1g + (size_t)(n0 + n) * 64 + jj) = val;
        }
    }

    // x = leaky(x1 @ Wl + bl)
    int j = tid & 63;
    int g = tid >> 6;
    float blj = bl[j];
    for (int i = 0; i < 16; ++i) {
        int n = g * 16 + i;
        float a = blj;
#pragma unroll
        for (int k = 0; k < 64; ++k) a += x1s[n][k] * wl[k][j];
        if (n0 + n < N) xg[(size_t)(n0 + n) * 64 + j] = leaky(a);
    }
}

// ---------------------------------------------------------------------------
// z = (x @ W) * dinv[:,None]   (64x64 weight)
__global__ __launch_bounds__(256) void k_xw(const float* __restrict__ xin,
                                            const float* __restrict__ W,
                                            const float* __restrict__ dinv,
                                            float* __restrict__ z, int N) {
    __shared__ float xsg[64][65];
    __shared__ float wg[64][65];
    const int tid = threadIdx.x;
    const int n0 = blockIdx.x * 64;
#pragma unroll
    for (int v = 0; v < 4; ++v) {
        int idx = tid + v * 256;
        int n = idx >> 4;
        int jj = (idx & 15) << 2;
        float4 xv = make_float4(0.f, 0.f, 0.f, 0.f);
        if (n0 + n < N) xv = *reinterpret_cast<const float4*>(xin + (size_t)(n0 + n) * 64 + jj);
        xsg[n][jj] = xv.x; xsg[n][jj + 1] = xv.y; xsg[n][jj + 2] = xv.z; xsg[n][jj + 3] = xv.w;
        float4 w = *reinterpret_cast<const float4*>(W + (size_t)n * 64 + jj);
        wg[n][jj] = w.x; wg[n][jj + 1] = w.y; wg[n][jj + 2] = w.z; wg[n][jj + 3] = w.w;
    }
    __syncthreads();
    int j = tid & 63;
    int g = tid >> 6;
    for (int i = 0; i < 16; ++i) {
        int n = g * 16 + i;
        float a = 0.f;
#pragma unroll
        for (int k = 0; k < 64; ++k) a += xsg[n][k] * wg[k][j];
        if (n0 + n < N) z[(size_t)(n0 + n) * 64 + j] = a * dinv[n0 + n];
    }
}

// Gather-based aggregation: one wave per node, lane = feature dim
__global__ __launch_bounds__(256) void k_agg(const float* __restrict__ z,
                                             const int* __restrict__ offs,
                                             const int* __restrict__ csr,
                                             const float* __restrict__ dinv,
                                             const float* __restrict__ bias,
                                             const float* __restrict__ x1,
                                             float* __restrict__ xout, int N) {
    int lane = threadIdx.x & 63;
    int c = blockIdx.x * 4 + (threadIdx.x >> 6);
    if (c >= N) return;
    float acc = z[(size_t)c * 64 + lane];  // self-loop term
    int s = offs[c], e = offs[c + 1];
    for (int j0 = s; j0 < e; j0 += 64) {
        int cnt = e - j0;
        if (cnt > 64) cnt = 64;
        int idx = (j0 + lane < e) ? csr[j0 + lane] : 0;
        for (int d = 0; d < cnt; ++d) {
            int r = __shfl(idx, d, 64);
            acc += z[(size_t)r * 64 + lane];
        }
    }
    xout[(size_t)c * 64 + lane] = dinv[c] * acc + bias[lane] + x1[(size_t)c * 64 + lane];
}

// ---------------------------------------------------------------------------
// head: h = leaky(x @ Wo1 + bo1); out = sigmoid(h @ Wo2 + bo2)
__global__ __launch_bounds__(256) void k_head(const float* __restrict__ xin,
                                              const float* __restrict__ Wo1,
                                              const float* __restrict__ bo1,
                                              const float* __restrict__ Wo2,
                                              const float* __restrict__ bo2,
                                              float* __restrict__ out, int N) {
    __shared__ float xsg[64][65];
    __shared__ float wg[64][65];
    __shared__ float hs[64][65];
    __shared__ float wo2[128];
    const int tid = threadIdx.x;
    const int n0 = blockIdx.x * 64;
#pragma unroll
    for (int v = 0; v < 4; ++v) {
        int idx = tid + v * 256;
        int n = idx >> 4;
        int jj = (idx & 15) << 2;
        float4 xv = make_float4(0.f, 0.f, 0.f, 0.f);
        if (n0 + n < N) xv = *reinterpret_cast<const float4*>(xin + (size_t)(n0 + n) * 64 + jj);
        xsg[n][jj] = xv.x; xsg[n][jj + 1] = xv.y; xsg[n][jj + 2] = xv.z; xsg[n][jj + 3] = xv.w;
        float4 w = *reinterpret_cast<const float4*>(Wo1 + (size_t)n * 64 + jj);
        wg[n][jj] = w.x; wg[n][jj + 1] = w.y; wg[n][jj + 2] = w.z; wg[n][jj + 3] = w.w;
    }
    if (tid < 128) wo2[tid] = Wo2[tid];
    __syncthreads();
    int j = tid & 63;
    int g = tid >> 6;
    float bj = bo1[j];
    for (int i = 0; i < 16; ++i) {
        int n = g * 16 + i;
        float a = bj;
#pragma unroll
        for (int k = 0; k < 64; ++k) a += xsg[n][k] * wg[k][j];
        hs[n][j] = leaky(a);
    }
    __syncthreads();
    if (tid < 128) {
        int n = tid >> 1;
        int j2 = tid & 1;
        float a = bo2[j2];
#pragma unroll
        for (int k = 0; k < 64; ++k) a += hs[n][k] * wo2[k * 2 + j2];
        if (n0 + n < N) out[(size_t)(n0 + n) * 2 + j2] = 1.f / (1.f + expf(-a));
    }
}

// ---------------------------------------------------------------------------
extern "C" void kernel_launch(void* const* d_in, const int* in_sizes, int n_in,
                              void* d_out, int out_size, void* d_ws, size_t ws_size,
                              hipStream_t stream) {
    const float* screen   = (const float*)d_in[0];
    const float* des      = (const float*)d_in[1];
    const float* tweet    = (const float*)d_in[2];
    const float* profile  = (const float*)d_in[3];
    const float* personal = (const float*)d_in[4];
    const int*   edge     = (const int*)d_in[5];
    const float* Ws  = (const float*)d_in[6],  *bs  = (const float*)d_in[7];
    const float* Wd  = (const float*)d_in[8],  *bd  = (const float*)d_in[9];
    const float* Wt  = (const float*)d_in[10], *bt  = (const float*)d_in[11];
    const float* Wp  = (const float*)d_in[12], *bp  = (const float*)d_in[13];
    const float* Wpe = (const float*)d_in[14], *bpe = (const float*)d_in[15];
    const float* Wl  = (const float*)d_in[16], *bl  = (const float*)d_in[17];
    const float* Wg1 = (const float*)d_in[18], *bg1 = (const float*)d_in[19];
    const float* Wg2 = (const float*)d_in[20], *bg2 = (const float*)d_in[21];
    const float* Wg3 = (const float*)d_in[22], *bg3 = (const float*)d_in[23];
    const float* Wo1 = (const float*)d_in[24], *bo1 = (const float*)d_in[25];
    const float* Wo2 = (const float*)d_in[26], *bo2 = (const float*)d_in[27];

    const int N = in_sizes[0] / 768;   // 50000
    const int E = in_sizes[5] / 2;     // 1600000
    const int* row = edge;
    const int* col = edge + E;

    size_t off = 0;
    auto alloc = [&](size_t bytes) -> void* {
        void* p = (char*)d_ws + off;
        off += (bytes + 255) & ~(size_t)255;
        return p;
    };
    const size_t NF = (size_t)N * 64;
    float* x1   = (float*)alloc(NF * 4);
    float* xa   = (float*)alloc(NF * 4);
    float* xb   = (float*)alloc(NF * 4);
    float* z    = (float*)alloc(NF * 4);
    float* dinv = (float*)alloc((size_t)N * 4);
    int* deg  = (int*)alloc((size_t)N * 4);
    int* part = (int*)alloc((size_t)N * 4);
    int* offs = (int*)alloc((size_t)(N + 1) * 4);
    int* pos  = (int*)alloc((size_t)N * 4);
    int* csr  = (int*)alloc((size_t)E * 4);
    const int NB = (N + 255) / 256;
    int* bsum = (int*)alloc((size_t)NB * 4);
    int* boff = (int*)alloc((size_t)NB * 4);
    (void)ws_size; (void)n_in; (void)out_size;

    // CSR build
    hipMemsetAsync(deg, 0, (size_t)N * 4, stream);
    k_deg<<<(E + 255) / 256, 256, 0, stream>>>(col, E, deg);
    k_scan_part<<<NB, 256, 0, stream>>>(deg, part, bsum, N);
    k_scan_sums<<<1, 256, 0, stream>>>(bsum, boff, NB, offs + N);
    k_scan_final<<<NB, 256, 0, stream>>>(part, boff, deg, offs, pos, dinv, N);
    k_fill<<<(E + 255) / 256, 256, 0, stream>>>(row, col, E, pos, csr);

    // front-end
    const int NGB = (N + 63) / 64;
    k_feat<<<NGB, 256, 0, stream>>>(screen, des, tweet, profile, personal,
                                    Ws, bs, Wd, bd, Wt, bt, Wp, bp, Wpe, bpe, Wl, bl,
                                    x1, xa, N);

    const int NAB = (N + 3) / 4;
    // layer 1: xa -> xb
    k_xw<<<NGB, 256, 0, stream>>>(xa, Wg1, dinv, z, N);
    k_agg<<<NAB, 256, 0, stream>>>(z, offs, csr, dinv, bg1, x1, xb, N);
    // layer 2: xb -> xa
    k_xw<<<NGB, 256, 0, stream>>>(xb, Wg2, dinv, z, N);
    k_agg<<<NAB, 256, 0, stream>>>(z, offs, csr, dinv, bg2, x1, xa, N);
    // layer 3: xa -> xb
    k_xw<<<NGB, 256, 0, stream>>>(xa, Wg3, dinv, z, N);
    k_agg<<<NAB, 256, 0, stream>>>(z, offs, csr, dinv, bg3, x1, xb, N);

    // head
    k_head<<<NGB, 256, 0, stream>>>(xb, Wo1, bo1, Wo2, bo2, (float*)d_out, N);
}